// Round 10
// baseline (211.436 us; speedup 1.0000x reference)
//
#include <hip/hip_runtime.h>

#define NCLS   4096
#define BATCHN 65536
#define TOPK   4096
#define ALPHA  2.0f

typedef float vfloat4 __attribute__((ext_vector_type(4)));

// ---------------------------------------------------------------------------
// Kernel 0: (a) detect whether link_table arrived as int32 (words all 0/1) or
// 1-byte bool (wave 0), and (b) zero the level-1 histogram (all 256 threads).
// ---------------------------------------------------------------------------
__global__ __launch_bounds__(256) void detect_and_zero_kernel(
    const unsigned int* __restrict__ lt, int* __restrict__ flag,
    unsigned int* __restrict__ ghist) {
    const int tid = threadIdx.x;
    #pragma unroll
    for (int i = 0; i < 16; ++i) ghist[i * 256 + tid] = 0u;
    if (tid < 64) {
        unsigned int bad = 0;
        for (int i = tid; i < 1024; i += 64) bad |= (lt[i] > 1u) ? 1u : 0u;
        unsigned long long mask = __ballot(bad != 0);
        if (tid == 0) flag[0] = (mask == 0ULL) ? 1 : 0;  // 1 => int32 storage
    }
}

__device__ inline void amax_comb(float& m, int& mi, float om, int omi) {
    // max value; ties -> smallest index (jnp.argmax takes first occurrence)
    if (om > m || (om == m && omi < mi)) { m = om; mi = omi; }
}

// ---------------------------------------------------------------------------
// Kernel 1: TWO rows per block, all 8 float4 loads prefetched up front
// (static, unconditional -> stays in VGPRs), rows computed back-to-back into
// separate LDS slots, ONE barrier, epilogues on wave0/wave1 in parallel.
// ---------------------------------------------------------------------------
__global__ __launch_bounds__(256) void row_loss_kernel(
    const float* __restrict__ yp, const int* __restrict__ yt,
    const unsigned char* __restrict__ lt, const int* __restrict__ flag,
    float* __restrict__ losses) {
    const int bA  = blockIdx.x * 2;
    const int bB  = bA + 1;
    const int tid = threadIdx.x;
    const int lane = tid & 63, wid = tid >> 6;

    const vfloat4* rowA = reinterpret_cast<const vfloat4*>(yp + (size_t)bA * NCLS);
    const vfloat4* rowB = reinterpret_cast<const vfloat4*>(yp + (size_t)bB * NCLS);

    // ---- prefetch both rows (8 independent 16B loads in flight)
    vfloat4 a0 = __builtin_nontemporal_load(&rowA[0 * 256 + tid]);
    vfloat4 a1 = __builtin_nontemporal_load(&rowA[1 * 256 + tid]);
    vfloat4 a2 = __builtin_nontemporal_load(&rowA[2 * 256 + tid]);
    vfloat4 a3 = __builtin_nontemporal_load(&rowA[3 * 256 + tid]);
    vfloat4 b0 = __builtin_nontemporal_load(&rowB[0 * 256 + tid]);
    vfloat4 b1 = __builtin_nontemporal_load(&rowB[1 * 256 + tid]);
    vfloat4 b2 = __builtin_nontemporal_load(&rowB[2 * 256 + tid]);
    vfloat4 b3 = __builtin_nontemporal_load(&rowB[3 * 256 + tid]);

    const int gtA = yt[bA];
    const int gtB = yt[bB];

    __shared__ float wmA[4], wsA[4]; __shared__ int wiA[4];
    __shared__ float wmB[4], wsB[4]; __shared__ int wiB[4];
    __shared__ float s_trueA, s_trueB;

    const int base = tid * 4;

    // ================= row A =================
    {
        float m = a0.x; int mi = base;
        if (a0.y > m) { m = a0.y; mi = base + 1; }
        if (a0.z > m) { m = a0.z; mi = base + 2; }
        if (a0.w > m) { m = a0.w; mi = base + 3; }
        if (a1.x > m) { m = a1.x; mi = 1024 + base + 0; }
        if (a1.y > m) { m = a1.y; mi = 1024 + base + 1; }
        if (a1.z > m) { m = a1.z; mi = 1024 + base + 2; }
        if (a1.w > m) { m = a1.w; mi = 1024 + base + 3; }
        if (a2.x > m) { m = a2.x; mi = 2048 + base + 0; }
        if (a2.y > m) { m = a2.y; mi = 2048 + base + 1; }
        if (a2.z > m) { m = a2.z; mi = 2048 + base + 2; }
        if (a2.w > m) { m = a2.w; mi = 2048 + base + 3; }
        if (a3.x > m) { m = a3.x; mi = 3072 + base + 0; }
        if (a3.y > m) { m = a3.y; mi = 3072 + base + 1; }
        if (a3.z > m) { m = a3.z; mi = 3072 + base + 2; }
        if (a3.w > m) { m = a3.w; mi = 3072 + base + 3; }

        float sx = __expf(a0.x - m) + __expf(a1.x - m) + __expf(a2.x - m) + __expf(a3.x - m);
        float sy = __expf(a0.y - m) + __expf(a1.y - m) + __expf(a2.y - m) + __expf(a3.y - m);
        float sz = __expf(a0.z - m) + __expf(a1.z - m) + __expf(a2.z - m) + __expf(a3.z - m);
        float sw = __expf(a0.w - m) + __expf(a1.w - m) + __expf(a2.w - m) + __expf(a3.w - m);
        float s = (sx + sy) + (sz + sw);

        if (tid == ((gtA >> 2) & 255)) {
            const int j = gtA >> 10, k = gtA & 3;
            vfloat4 vv = (j == 0) ? a0 : (j == 1) ? a1 : (j == 2) ? a2 : a3;
            s_trueA = (k == 0) ? vv.x : (k == 1) ? vv.y : (k == 2) ? vv.z : vv.w;
        }

        float mw = m; int miw = mi;
        #pragma unroll
        for (int off = 32; off > 0; off >>= 1) {
            float om  = __shfl_xor(mw, off, 64);
            int   omi = __shfl_xor(miw, off, 64);
            amax_comb(mw, miw, om, omi);
        }
        s *= __expf(m - mw);
        #pragma unroll
        for (int off = 32; off > 0; off >>= 1) s += __shfl_xor(s, off, 64);
        if (lane == 0) { wmA[wid] = mw; wiA[wid] = miw; wsA[wid] = s; }
    }

    // ================= row B =================
    {
        float m = b0.x; int mi = base;
        if (b0.y > m) { m = b0.y; mi = base + 1; }
        if (b0.z > m) { m = b0.z; mi = base + 2; }
        if (b0.w > m) { m = b0.w; mi = base + 3; }
        if (b1.x > m) { m = b1.x; mi = 1024 + base + 0; }
        if (b1.y > m) { m = b1.y; mi = 1024 + base + 1; }
        if (b1.z > m) { m = b1.z; mi = 1024 + base + 2; }
        if (b1.w > m) { m = b1.w; mi = 1024 + base + 3; }
        if (b2.x > m) { m = b2.x; mi = 2048 + base + 0; }
        if (b2.y > m) { m = b2.y; mi = 2048 + base + 1; }
        if (b2.z > m) { m = b2.z; mi = 2048 + base + 2; }
        if (b2.w > m) { m = b2.w; mi = 2048 + base + 3; }
        if (b3.x > m) { m = b3.x; mi = 3072 + base + 0; }
        if (b3.y > m) { m = b3.y; mi = 3072 + base + 1; }
        if (b3.z > m) { m = b3.z; mi = 3072 + base + 2; }
        if (b3.w > m) { m = b3.w; mi = 3072 + base + 3; }

        float sx = __expf(b0.x - m) + __expf(b1.x - m) + __expf(b2.x - m) + __expf(b3.x - m);
        float sy = __expf(b0.y - m) + __expf(b1.y - m) + __expf(b2.y - m) + __expf(b3.y - m);
        float sz = __expf(b0.z - m) + __expf(b1.z - m) + __expf(b2.z - m) + __expf(b3.z - m);
        float sw = __expf(b0.w - m) + __expf(b1.w - m) + __expf(b2.w - m) + __expf(b3.w - m);
        float s = (sx + sy) + (sz + sw);

        if (tid == ((gtB >> 2) & 255)) {
            const int j = gtB >> 10, k = gtB & 3;
            vfloat4 vv = (j == 0) ? b0 : (j == 1) ? b1 : (j == 2) ? b2 : b3;
            s_trueB = (k == 0) ? vv.x : (k == 1) ? vv.y : (k == 2) ? vv.z : vv.w;
        }

        float mw = m; int miw = mi;
        #pragma unroll
        for (int off = 32; off > 0; off >>= 1) {
            float om  = __shfl_xor(mw, off, 64);
            int   omi = __shfl_xor(miw, off, 64);
            amax_comb(mw, miw, om, omi);
        }
        s *= __expf(m - mw);
        #pragma unroll
        for (int off = 32; off > 0; off >>= 1) s += __shfl_xor(s, off, 64);
        if (lane == 0) { wmB[wid] = mw; wiB[wid] = miw; wsB[wid] = s; }
    }

    __syncthreads();                     // the ONLY barrier

    if (tid == 0) {                      // epilogue A on wave 0
        float M = wmA[0]; int P = wiA[0];
        amax_comb(M, P, wmA[1], wiA[1]);
        amax_comb(M, P, wmA[2], wiA[2]);
        amax_comb(M, P, wmA[3], wiA[3]);
        const float tot = wsA[0] * __expf(wmA[0] - M) + wsA[1] * __expf(wmA[1] - M) +
                          wsA[2] * __expf(wmA[2] - M) + wsA[3] * __expf(wmA[3] - M);
        const float ce = logf(tot) + M - s_trueA;
        float factor = 1.0f;
        if (P != gtA) {
            const size_t li = (size_t)gtA * NCLS + (size_t)P;
            const int linked = flag[0] ? ((const int*)lt)[li] : (int)lt[li];
            if (linked) factor = ALPHA;
        }
        losses[bA] = factor * ce;
    } else if (tid == 64) {              // epilogue B on wave 1 (parallel)
        float M = wmB[0]; int P = wiB[0];
        amax_comb(M, P, wmB[1], wiB[1]);
        amax_comb(M, P, wmB[2], wiB[2]);
        amax_comb(M, P, wmB[3], wiB[3]);
        const float tot = wsB[0] * __expf(wmB[0] - M) + wsB[1] * __expf(wmB[1] - M) +
                          wsB[2] * __expf(wmB[2] - M) + wsB[3] * __expf(wmB[3] - M);
        const float ce = logf(tot) + M - s_trueB;
        float factor = 1.0f;
        if (P != gtB) {
            const size_t li = (size_t)gtB * NCLS + (size_t)P;
            const int linked = flag[0] ? ((const int*)lt)[li] : (int)lt[li];
            if (linked) factor = ALPHA;
        }
        losses[bB] = factor * ce;
    }
}

// ---------------------------------------------------------------------------
// Kernel A: level-1 histogram (bits [31:20]) via per-block privatized LDS
// hists on 16 CUs, merged with global atomics on NON-ZERO bins only.
// ---------------------------------------------------------------------------
__global__ __launch_bounds__(1024) void hist_l1_kernel(
    const float* __restrict__ losses, unsigned int* __restrict__ ghist) {
    __shared__ unsigned int hist[4096];
    const int tid = threadIdx.x;
    for (int i = tid; i < 4096; i += 1024) hist[i] = 0;
    __syncthreads();
    const int base = blockIdx.x * 4096;       // 16 blocks x 4096 elements
    #pragma unroll
    for (int k = 0; k < 4; ++k) {
        const unsigned int key = __float_as_uint(losses[base + k * 1024 + tid]);
        atomicAdd(&hist[key >> 20], 1u);
    }
    __syncthreads();
    for (int i = tid; i < 4096; i += 1024) {
        const unsigned int h = hist[i];
        if (h) atomicAdd(&ghist[i], h);
    }
}

// ---------------------------------------------------------------------------
// Kernel 2: exact mean of top-K. Level-1 hist precomputed (kernel A);
// threshold scans via single-wave suffix-scan + ballot; levels 2/3 plain
// LDS atomics (prefix-filtered keys spread uniformly -> low contention).
// ---------------------------------------------------------------------------
__device__ inline void scan4096(const unsigned int* hist, unsigned int kneed,
                                int* s_bin, unsigned int* s_kneed, int tid) {
    if (tid < 64) {
        // stage 1: super-bins of 64
        unsigned int sb = 0;
        #pragma unroll 8
        for (int i = 0; i < 64; ++i) sb += hist[tid * 64 + i];
        unsigned int GS = sb;  // suffix sum over super-bins
        #pragma unroll
        for (int off = 1; off < 64; off <<= 1) {
            unsigned int o = __shfl_down(GS, off, 64);
            GS += (tid + off < 64) ? o : 0u;
        }
        unsigned long long b1 = __ballot(GS >= kneed);
        const int sstar = 63 - __clzll(b1);
        const unsigned int A1 = (sstar < 63) ? __shfl(GS, sstar + 1, 64) : 0u;

        // stage 2: within super-bin sstar
        unsigned int W = hist[sstar * 64 + tid];
        #pragma unroll
        for (int off = 1; off < 64; off <<= 1) {
            unsigned int o = __shfl_down(W, off, 64);
            W += (tid + off < 64) ? o : 0u;
        }
        unsigned long long b2 = __ballot(A1 + W >= kneed);
        const int tstar = 63 - __clzll(b2);
        const unsigned int above = A1 + ((tstar < 63) ? __shfl(W, tstar + 1, 64) : 0u);
        if (tid == 0) { *s_bin = sstar * 64 + tstar; *s_kneed = kneed - above; }
    }
}

__global__ __launch_bounds__(1024) void topk_mean_kernel(
    const float* __restrict__ losses, const unsigned int* __restrict__ ghist,
    float* __restrict__ out) {
    __shared__ unsigned int hist[4096];
    __shared__ int          s_bin;
    __shared__ unsigned int s_kneed;
    __shared__ double       dsum[16];
    __shared__ unsigned int dcnt[16];

    const int tid = threadIdx.x;
    const int lane = tid & 63;
    const int N = BATCHN, K = TOPK;

    // ---- level 1: bits [31:20] (hist precomputed by kernel A)
    for (int i = tid; i < 4096; i += 1024) hist[i] = ghist[i];
    __syncthreads();
    scan4096(hist, (unsigned int)K, &s_bin, &s_kneed, tid);
    __syncthreads();
    const unsigned int t1 = (unsigned int)s_bin;
    const unsigned int k1 = s_kneed;
    __syncthreads();

    // ---- level 2: bits [19:8] among keys with key>>20 == t1
    for (int i = tid; i < 4096; i += 1024) hist[i] = 0;
    __syncthreads();
    for (int i = tid; i < N; i += 1024) {
        const unsigned int key = __float_as_uint(losses[i]);
        if ((key >> 20) == t1) atomicAdd(&hist[(key >> 8) & 0xFFFu], 1u);
    }
    __syncthreads();
    scan4096(hist, k1, &s_bin, &s_kneed, tid);
    __syncthreads();
    const unsigned int t2 = (unsigned int)s_bin;
    const unsigned int k2 = s_kneed;
    const unsigned int pref = (t1 << 12) | t2;  // 24-bit prefix
    __syncthreads();

    // ---- level 3: bits [7:0] among keys with key>>8 == pref
    for (int i = tid; i < 256; i += 1024) hist[i] = 0;
    __syncthreads();
    for (int i = tid; i < N; i += 1024) {
        const unsigned int key = __float_as_uint(losses[i]);
        if ((key >> 8) == pref) atomicAdd(&hist[key & 0xFFu], 1u);
    }
    __syncthreads();
    if (tid < 64) {
        // super-bins of 4
        unsigned int sb = hist[tid * 4] + hist[tid * 4 + 1] +
                          hist[tid * 4 + 2] + hist[tid * 4 + 3];
        unsigned int GS = sb;
        #pragma unroll
        for (int off = 1; off < 64; off <<= 1) {
            unsigned int o = __shfl_down(GS, off, 64);
            GS += (tid + off < 64) ? o : 0u;
        }
        unsigned long long b1 = __ballot(GS >= k2);
        const int sstar = 63 - __clzll(b1);
        const unsigned int A1 = (sstar < 63) ? __shfl(GS, sstar + 1, 64) : 0u;
        if (tid == 0) {
            unsigned int G = A1; int tstar = sstar * 4;
            for (int j = 3; j >= 0; --j) {
                const int bin = sstar * 4 + j;
                if (G + hist[bin] >= k2) { tstar = bin; break; }
                G += hist[bin];
            }
            s_bin = tstar;
        }
    }
    __syncthreads();
    const unsigned int T = (pref << 8) | (unsigned int)s_bin;  // threshold bits

    // ---- final: sum strictly-greater, fill remainder with T (ties)
    double local = 0.0; unsigned int cgt = 0;
    for (int i = tid; i < N; i += 1024) {
        const unsigned int key = __float_as_uint(losses[i]);
        if (key > T) { local += (double)__uint_as_float(key); cgt++; }
    }
    const int wid = tid >> 6;
    #pragma unroll
    for (int off = 32; off > 0; off >>= 1) {
        local += __shfl_down(local, off, 64);
        cgt   += __shfl_down(cgt, off, 64);
    }
    if (lane == 0) { dsum[wid] = local; dcnt[wid] = cgt; }
    __syncthreads();
    if (tid == 0) {
        double tot = 0.0; unsigned int ngt = 0;
        for (int w = 0; w < 16; ++w) { tot += dsum[w]; ngt += dcnt[w]; }
        tot += (double)(K - ngt) * (double)__uint_as_float(T);
        out[0] = (float)(tot / (double)K);
    }
}

// ---------------------------------------------------------------------------
extern "C" void kernel_launch(void* const* d_in, const int* in_sizes, int n_in,
                              void* d_out, int out_size, void* d_ws, size_t ws_size,
                              hipStream_t stream) {
    const float* y_pred     = (const float*)d_in[0];
    const int* y_true       = (const int*)d_in[1];
    const unsigned char* lt = (const unsigned char*)d_in[2];
    float* out              = (float*)d_out;

    int*          flag   = (int*)d_ws;
    unsigned int* ghist  = (unsigned int*)((char*)d_ws + 1024);   // 16 KB
    float*        losses = (float*)((char*)d_ws + 32768);         // 256 KB

    detect_and_zero_kernel<<<1, 256, 0, stream>>>((const unsigned int*)lt, flag, ghist);
    row_loss_kernel<<<BATCHN / 2, 256, 0, stream>>>(y_pred, y_true, lt, flag, losses);
    hist_l1_kernel<<<16, 1024, 0, stream>>>(losses, ghist);
    topk_mean_kernel<<<1, 1024, 0, stream>>>(losses, ghist, out);
}

// Round 11
// 205.220 us; speedup vs baseline: 1.0303x; 1.0303x over previous
//
#include <hip/hip_runtime.h>

#define NCLS   4096
#define BATCHN 65536
#define TOPK   4096
#define ALPHA  2.0f

typedef float vfloat4 __attribute__((ext_vector_type(4)));

// ---------------------------------------------------------------------------
// Kernel 0: (a) detect whether link_table arrived as int32 (words all 0/1) or
// 1-byte bool (wave 0), and (b) zero the level-1 histogram (all 256 threads).
// ---------------------------------------------------------------------------
__global__ __launch_bounds__(256) void detect_and_zero_kernel(
    const unsigned int* __restrict__ lt, int* __restrict__ flag,
    unsigned int* __restrict__ ghist) {
    const int tid = threadIdx.x;
    #pragma unroll
    for (int i = 0; i < 16; ++i) ghist[i * 256 + tid] = 0u;
    if (tid < 64) {
        unsigned int bad = 0;
        for (int i = tid; i < 1024; i += 64) bad |= (lt[i] > 1u) ? 1u : 0u;
        unsigned long long mask = __ballot(bad != 0);
        if (tid == 0) flag[0] = (mask == 0ULL) ? 1 : 0;  // 1 => int32 storage
    }
}

__device__ inline void amax_comb(float& m, int& mi, float om, int omi) {
    // max value; ties -> smallest index (jnp.argmax takes first occurrence)
    if (om > m || (om == m && omi < mi)) { m = om; mi = omi; }
}

// ---------------------------------------------------------------------------
// Kernel 1: one block per row (round-9 configuration — best measured:
// 206.8us total, row_loss ~5.8 TB/s). NT loads on read-once y_pred.
// 2-rows/block variant A/B-tested in round 10: -2.2% (occupancy loss).
// ---------------------------------------------------------------------------
__global__ __launch_bounds__(256) void row_loss_kernel(
    const float* __restrict__ yp, const int* __restrict__ yt,
    const unsigned char* __restrict__ lt, const int* __restrict__ flag,
    float* __restrict__ losses) {
    const int b   = blockIdx.x;
    const int tid = threadIdx.x;
    const vfloat4* row = reinterpret_cast<const vfloat4*>(yp + (size_t)b * NCLS);

    vfloat4 v0 = __builtin_nontemporal_load(&row[0 * 256 + tid]);
    vfloat4 v1 = __builtin_nontemporal_load(&row[1 * 256 + tid]);
    vfloat4 v2 = __builtin_nontemporal_load(&row[2 * 256 + tid]);
    vfloat4 v3 = __builtin_nontemporal_load(&row[3 * 256 + tid]);

    // local max/argmax; columns for chunk j are j*1024 + tid*4 + k (ascending)
    float m = -3.4e38f; int mi = 0;
    {
        const int c0 = tid * 4;
        if (v0.x > m) { m = v0.x; mi = c0 + 0; }
        if (v0.y > m) { m = v0.y; mi = c0 + 1; }
        if (v0.z > m) { m = v0.z; mi = c0 + 2; }
        if (v0.w > m) { m = v0.w; mi = c0 + 3; }
        const int c1 = 1024 + tid * 4;
        if (v1.x > m) { m = v1.x; mi = c1 + 0; }
        if (v1.y > m) { m = v1.y; mi = c1 + 1; }
        if (v1.z > m) { m = v1.z; mi = c1 + 2; }
        if (v1.w > m) { m = v1.w; mi = c1 + 3; }
        const int c2 = 2048 + tid * 4;
        if (v2.x > m) { m = v2.x; mi = c2 + 0; }
        if (v2.y > m) { m = v2.y; mi = c2 + 1; }
        if (v2.z > m) { m = v2.z; mi = c2 + 2; }
        if (v2.w > m) { m = v2.w; mi = c2 + 3; }
        const int c3 = 3072 + tid * 4;
        if (v3.x > m) { m = v3.x; mi = c3 + 0; }
        if (v3.y > m) { m = v3.y; mi = c3 + 1; }
        if (v3.z > m) { m = v3.z; mi = c3 + 2; }
        if (v3.w > m) { m = v3.w; mi = c3 + 3; }
    }

    // wave (64-lane) argmax reduce
    #pragma unroll
    for (int off = 32; off > 0; off >>= 1) {
        float om  = __shfl_down(m, off, 64);
        int   omi = __shfl_down(mi, off, 64);
        amax_comb(m, mi, om, omi);
    }

    __shared__ float wmax[4];
    __shared__ int   wmi[4];
    __shared__ float wsum[4];
    __shared__ float s_M;
    __shared__ int   s_pred;
    __shared__ float s_true;

    const int wid = tid >> 6, lane = tid & 63;
    if (lane == 0) { wmax[wid] = m; wmi[wid] = mi; }
    __syncthreads();
    if (tid == 0) {
        float M = wmax[0]; int P = wmi[0];
        amax_comb(M, P, wmax[1], wmi[1]);
        amax_comb(M, P, wmax[2], wmi[2]);
        amax_comb(M, P, wmax[3], wmi[3]);
        s_M = M; s_pred = P;
    }
    __syncthreads();
    const float M = s_M;

    float sum = 0.f;
    sum += __expf(v0.x - M); sum += __expf(v0.y - M);
    sum += __expf(v0.z - M); sum += __expf(v0.w - M);
    sum += __expf(v1.x - M); sum += __expf(v1.y - M);
    sum += __expf(v1.z - M); sum += __expf(v1.w - M);
    sum += __expf(v2.x - M); sum += __expf(v2.y - M);
    sum += __expf(v2.z - M); sum += __expf(v2.w - M);
    sum += __expf(v3.x - M); sum += __expf(v3.y - M);
    sum += __expf(v3.z - M); sum += __expf(v3.w - M);

    #pragma unroll
    for (int off = 32; off > 0; off >>= 1) sum += __shfl_down(sum, off, 64);

    const int gt = yt[b];
    // owner of column gt: chunk j = gt>>10, thread (gt>>2)&255, slot gt&3
    if (tid == ((gt >> 2) & 255)) {
        const int j = gt >> 10, k = gt & 3;
        vfloat4 vv = (j == 0) ? v0 : (j == 1) ? v1 : (j == 2) ? v2 : v3;
        float t = (k == 0) ? vv.x : (k == 1) ? vv.y : (k == 2) ? vv.z : vv.w;
        s_true = t;
    }
    if (lane == 0) wsum[wid] = sum;
    __syncthreads();

    if (tid == 0) {
        float tot = wsum[0] + wsum[1] + wsum[2] + wsum[3];
        float ce  = logf(tot) + s_M - s_true;
        int pred  = s_pred;
        float factor = 1.0f;
        if (pred != gt) {
            size_t idx = (size_t)gt * NCLS + (size_t)pred;
            int linked = flag[0] ? ((const int*)lt)[idx] : (int)lt[idx];
            if (linked) factor = ALPHA;
        }
        losses[b] = factor * ce;
    }
}

// ---------------------------------------------------------------------------
// Kernel A: level-1 histogram (bits [31:20]) via per-block privatized LDS
// hists on 16 CUs, merged with global atomics on NON-ZERO bins only.
// ---------------------------------------------------------------------------
__global__ __launch_bounds__(1024) void hist_l1_kernel(
    const float* __restrict__ losses, unsigned int* __restrict__ ghist) {
    __shared__ unsigned int hist[4096];
    const int tid = threadIdx.x;
    for (int i = tid; i < 4096; i += 1024) hist[i] = 0;
    __syncthreads();
    const int base = blockIdx.x * 4096;       // 16 blocks x 4096 elements
    #pragma unroll
    for (int k = 0; k < 4; ++k) {
        const unsigned int key = __float_as_uint(losses[base + k * 1024 + tid]);
        atomicAdd(&hist[key >> 20], 1u);
    }
    __syncthreads();
    for (int i = tid; i < 4096; i += 1024) {
        const unsigned int h = hist[i];
        if (h) atomicAdd(&ghist[i], h);
    }
}

// ---------------------------------------------------------------------------
// Kernel 2: exact mean of top-K. Level-1 hist precomputed (kernel A);
// threshold scans via single-wave suffix-scan + ballot; levels 2/3 plain
// LDS atomics (prefix-filtered keys spread uniformly -> low contention).
// ---------------------------------------------------------------------------
__device__ inline void scan4096(const unsigned int* hist, unsigned int kneed,
                                int* s_bin, unsigned int* s_kneed, int tid) {
    if (tid < 64) {
        // stage 1: super-bins of 64
        unsigned int sb = 0;
        #pragma unroll 8
        for (int i = 0; i < 64; ++i) sb += hist[tid * 64 + i];
        unsigned int GS = sb;  // suffix sum over super-bins
        #pragma unroll
        for (int off = 1; off < 64; off <<= 1) {
            unsigned int o = __shfl_down(GS, off, 64);
            GS += (tid + off < 64) ? o : 0u;
        }
        unsigned long long b1 = __ballot(GS >= kneed);
        const int sstar = 63 - __clzll(b1);
        const unsigned int A1 = (sstar < 63) ? __shfl(GS, sstar + 1, 64) : 0u;

        // stage 2: within super-bin sstar
        unsigned int W = hist[sstar * 64 + tid];
        #pragma unroll
        for (int off = 1; off < 64; off <<= 1) {
            unsigned int o = __shfl_down(W, off, 64);
            W += (tid + off < 64) ? o : 0u;
        }
        unsigned long long b2 = __ballot(A1 + W >= kneed);
        const int tstar = 63 - __clzll(b2);
        const unsigned int above = A1 + ((tstar < 63) ? __shfl(W, tstar + 1, 64) : 0u);
        if (tid == 0) { *s_bin = sstar * 64 + tstar; *s_kneed = kneed - above; }
    }
}

__global__ __launch_bounds__(1024) void topk_mean_kernel(
    const float* __restrict__ losses, const unsigned int* __restrict__ ghist,
    float* __restrict__ out) {
    __shared__ unsigned int hist[4096];
    __shared__ int          s_bin;
    __shared__ unsigned int s_kneed;
    __shared__ double       dsum[16];
    __shared__ unsigned int dcnt[16];

    const int tid = threadIdx.x;
    const int lane = tid & 63;
    const int N = BATCHN, K = TOPK;

    // ---- level 1: bits [31:20] (hist precomputed by kernel A)
    for (int i = tid; i < 4096; i += 1024) hist[i] = ghist[i];
    __syncthreads();
    scan4096(hist, (unsigned int)K, &s_bin, &s_kneed, tid);
    __syncthreads();
    const unsigned int t1 = (unsigned int)s_bin;
    const unsigned int k1 = s_kneed;
    __syncthreads();

    // ---- level 2: bits [19:8] among keys with key>>20 == t1
    for (int i = tid; i < 4096; i += 1024) hist[i] = 0;
    __syncthreads();
    for (int i = tid; i < N; i += 1024) {
        const unsigned int key = __float_as_uint(losses[i]);
        if ((key >> 20) == t1) atomicAdd(&hist[(key >> 8) & 0xFFFu], 1u);
    }
    __syncthreads();
    scan4096(hist, k1, &s_bin, &s_kneed, tid);
    __syncthreads();
    const unsigned int t2 = (unsigned int)s_bin;
    const unsigned int k2 = s_kneed;
    const unsigned int pref = (t1 << 12) | t2;  // 24-bit prefix
    __syncthreads();

    // ---- level 3: bits [7:0] among keys with key>>8 == pref
    for (int i = tid; i < 256; i += 1024) hist[i] = 0;
    __syncthreads();
    for (int i = tid; i < N; i += 1024) {
        const unsigned int key = __float_as_uint(losses[i]);
        if ((key >> 8) == pref) atomicAdd(&hist[key & 0xFFu], 1u);
    }
    __syncthreads();
    if (tid < 64) {
        // super-bins of 4
        unsigned int sb = hist[tid * 4] + hist[tid * 4 + 1] +
                          hist[tid * 4 + 2] + hist[tid * 4 + 3];
        unsigned int GS = sb;
        #pragma unroll
        for (int off = 1; off < 64; off <<= 1) {
            unsigned int o = __shfl_down(GS, off, 64);
            GS += (tid + off < 64) ? o : 0u;
        }
        unsigned long long b1 = __ballot(GS >= k2);
        const int sstar = 63 - __clzll(b1);
        const unsigned int A1 = (sstar < 63) ? __shfl(GS, sstar + 1, 64) : 0u;
        if (tid == 0) {
            unsigned int G = A1; int tstar = sstar * 4;
            for (int j = 3; j >= 0; --j) {
                const int bin = sstar * 4 + j;
                if (G + hist[bin] >= k2) { tstar = bin; break; }
                G += hist[bin];
            }
            s_bin = tstar;
        }
    }
    __syncthreads();
    const unsigned int T = (pref << 8) | (unsigned int)s_bin;  // threshold bits

    // ---- final: sum strictly-greater, fill remainder with T (ties)
    double local = 0.0; unsigned int cgt = 0;
    for (int i = tid; i < N; i += 1024) {
        const unsigned int key = __float_as_uint(losses[i]);
        if (key > T) { local += (double)__uint_as_float(key); cgt++; }
    }
    const int wid = tid >> 6;
    #pragma unroll
    for (int off = 32; off > 0; off >>= 1) {
        local += __shfl_down(local, off, 64);
        cgt   += __shfl_down(cgt, off, 64);
    }
    if (lane == 0) { dsum[wid] = local; dcnt[wid] = cgt; }
    __syncthreads();
    if (tid == 0) {
        double tot = 0.0; unsigned int ngt = 0;
        for (int w = 0; w < 16; ++w) { tot += dsum[w]; ngt += dcnt[w]; }
        tot += (double)(K - ngt) * (double)__uint_as_float(T);
        out[0] = (float)(tot / (double)K);
    }
}

// ---------------------------------------------------------------------------
extern "C" void kernel_launch(void* const* d_in, const int* in_sizes, int n_in,
                              void* d_out, int out_size, void* d_ws, size_t ws_size,
                              hipStream_t stream) {
    const float* y_pred     = (const float*)d_in[0];
    const int* y_true       = (const int*)d_in[1];
    const unsigned char* lt = (const unsigned char*)d_in[2];
    float* out              = (float*)d_out;

    int*          flag   = (int*)d_ws;
    unsigned int* ghist  = (unsigned int*)((char*)d_ws + 1024);   // 16 KB
    float*        losses = (float*)((char*)d_ws + 32768);         // 256 KB

    detect_and_zero_kernel<<<1, 256, 0, stream>>>((const unsigned int*)lt, flag, ghist);
    row_loss_kernel<<<BATCHN, 256, 0, stream>>>(y_pred, y_true, lt, flag, losses);
    hist_l1_kernel<<<16, 1024, 0, stream>>>(losses, ghist);
    topk_mean_kernel<<<1, 1024, 0, stream>>>(losses, ghist, out);
}